// Round 9
// baseline (174.286 us; speedup 1.0000x reference)
//
#include <hip/hip_runtime.h>
#include <hip/hip_cooperative_groups.h>

namespace cg = cooperative_groups;

// LinearAttention (Performer/FAVOR+): B=8, T=S=8192, F=D=64, M=128 (2M=256 features)
// R9: dispatch-count reduction. Two cooperative kernels partitioned by register
// profile (R5's failure was merging high- and low-pressure phases under one
// launch_bounds): k1(256,2) = setup -> sync -> kv; k2(256,4) = finalize -> sync
// -> qkv. Bodies byte-identical to R8. Full fallback to the R8 4-dispatch path.
//
// MFMA 16x16x32 bf16 layouts (measured, learn_hip m89/m91):
//   A-frag: lane holds A[m = lane&15][k = (lane>>4)*8 + j], j=0..7
//   B-frag: lane holds B[k = (lane>>4)*8 + j][n = lane&15]
//   C/D   : lane holds D[row = (lane>>4)*4 + reg][col = lane&15], reg=0..3

constexpr int NB = 8;
constexpr int NT = 8192;
constexpr float EPSF = 1e-9f;
constexpr float SCALE = 0.0625f;  // 1/sqrt(2*128)

typedef short s8v __attribute__((ext_vector_type(8)));
typedef short s4v __attribute__((ext_vector_type(4)));
typedef float f4v __attribute__((ext_vector_type(4)));

__device__ inline f4v mfma16(s8v a, s8v b, f4v c) {
  return __builtin_amdgcn_mfma_f32_16x16x32_bf16(a, b, c, 0, 0, 0);
}

__device__ inline short bf16_rne(float f) {
  unsigned u = __builtin_bit_cast(unsigned, f);
  u += 0x7fffu + ((u >> 16) & 1u);
  return (short)(u >> 16);
}
__device__ inline float bf16_to_f(short h) {
  unsigned u = ((unsigned)(unsigned short)h) << 16;
  return __builtin_bit_cast(float, u);
}
__device__ inline unsigned pack2(short lo, short hi) {
  return (unsigned)(unsigned short)lo | ((unsigned)(unsigned short)hi << 16);
}

// ---- omega split (Markidis 3-term: keeps pre-exp x.omega at ~fp32 accuracy) ----
__device__ inline void omega_split_item(const float* __restrict__ omega,
                                        short* __restrict__ oh, short* __restrict__ ol,
                                        int i) {
  float w = omega[i];
  short h = bf16_rne(w);
  oh[i] = h;
  ol[i] = bf16_rne(w - bf16_to_f(h));
}

__global__ void setup_omega(const float* __restrict__ omega,
                            short* __restrict__ oh, short* __restrict__ ol) {
  int i = blockIdx.x * 256 + threadIdx.x;
  if (i >= 128 * 64) return;
  omega_split_item(omega, oh, ol, i);
}

// ---- shared phi helpers ----
struct PhiRows {
  s8v ah0, al0, ah1, al1;  // x fragments (hi/lo) for ksteps 0,1
  float ssr[4];            // |x_row|^2/2 for rows quad*4+reg (C-row indexed)
  float ss;                // |x_row|^2/2 for this lane's own row (lane&15)
};

__device__ inline void split8(f4v a, f4v b, s8v& h, s8v& l) {
  float v[8] = {a.x, a.y, a.z, a.w, b.x, b.y, b.z, b.w};
#pragma unroll
  for (int j = 0; j < 8; ++j) {
    short hh = bf16_rne(v[j]);
    h[j] = hh;
    l[j] = bf16_rne(v[j] - bf16_to_f(hh));
  }
}

__device__ inline void load_phi_rows(const float* __restrict__ xrow_base, int lane, PhiRows& P) {
  const int r = lane & 15, q = lane >> 4;
  const float* p = xrow_base + r * 64 + q * 8;
  f4v u0 = *(const f4v*)(p);
  f4v u1 = *(const f4v*)(p + 4);
  f4v u2 = *(const f4v*)(p + 32);
  f4v u3 = *(const f4v*)(p + 36);
  float ss = u0.x * u0.x + u0.y * u0.y + u0.z * u0.z + u0.w * u0.w
           + u1.x * u1.x + u1.y * u1.y + u1.z * u1.z + u1.w * u1.w
           + u2.x * u2.x + u2.y * u2.y + u2.z * u2.z + u2.w * u2.w
           + u3.x * u3.x + u3.y * u3.y + u3.z * u3.z + u3.w * u3.w;
  ss += __shfl_xor(ss, 16, 64);
  ss += __shfl_xor(ss, 32, 64);
  ss *= 0.5f;
  P.ss = ss;
#pragma unroll
  for (int reg = 0; reg < 4; ++reg) P.ssr[reg] = __shfl(ss, q * 4 + reg, 64);
  split8(u0, u1, P.ah0, P.al0);
  split8(u2, u3, P.ah1, P.al1);
}

// xw C-tile, A = x rows (C: row = x-row q*4+reg, col = omega-row lane&15)
__device__ inline f4v phi_xw_tile(const PhiRows& P, const short* __restrict__ oh,
                                  const short* __restrict__ ol, int f0, int lane) {
  const int fr = f0 + (lane & 15);
  const int q = lane >> 4;
  s8v bh0 = *(const s8v*)(oh + fr * 64 + q * 8);
  s8v bh1 = *(const s8v*)(oh + fr * 64 + 32 + q * 8);
  s8v bl0 = *(const s8v*)(ol + fr * 64 + q * 8);
  s8v bl1 = *(const s8v*)(ol + fr * 64 + 32 + q * 8);
  f4v c = {0.f, 0.f, 0.f, 0.f};
  c = mfma16(P.ah0, bh0, c);
  c = mfma16(P.ah1, bh1, c);
  c = mfma16(P.al0, bh0, c);
  c = mfma16(P.al1, bh1, c);
  c = mfma16(P.ah0, bl0, c);
  c = mfma16(P.ah1, bl1, c);
  return c;
}

// xw C-tile, swapped: A = omega rows (C: row = omega-row q*4+reg, col = x-row lane&15).
__device__ inline f4v phi_xw_tile_T(const PhiRows& P, const short* __restrict__ oh,
                                    const short* __restrict__ ol, int f0, int lane) {
  const int fr = f0 + (lane & 15);
  const int q = lane >> 4;
  s8v ah0 = *(const s8v*)(oh + fr * 64 + q * 8);
  s8v ah1 = *(const s8v*)(oh + fr * 64 + 32 + q * 8);
  s8v al0 = *(const s8v*)(ol + fr * 64 + q * 8);
  s8v al1 = *(const s8v*)(ol + fr * 64 + 32 + q * 8);
  f4v c = {0.f, 0.f, 0.f, 0.f};
  c = mfma16(ah0, P.ah0, c);
  c = mfma16(ah1, P.ah1, c);
  c = mfma16(al0, P.ah0, c);
  c = mfma16(al1, P.ah1, c);
  c = mfma16(ah0, P.al0, c);
  c = mfma16(ah1, P.al1, c);
  return c;
}

// Two 16-row C-tiles (row = k-local, col = n) -> one K=32 B/A-layout frag.
// (HW-verified by R7/R8 passing with this transform.)
__device__ inline s8v bfrag_shuffle(unsigned g0d0, unsigned g0d1,
                                    unsigned g1d0, unsigned g1d1, int lane) {
  const int sb = ((lane & 16) ? 32 : 0) | (lane & 15);
  int a0 = __shfl((int)g0d0, sb, 64);
  int a1 = __shfl((int)g0d1, sb, 64);
  int a2 = __shfl((int)g0d0, sb + 16, 64);
  int a3 = __shfl((int)g0d1, sb + 16, 64);
  int b0 = __shfl((int)g1d0, sb, 64);
  int b1 = __shfl((int)g1d1, sb, 64);
  int b2 = __shfl((int)g1d0, sb + 16, 64);
  int b3 = __shfl((int)g1d1, sb + 16, 64);
  const bool hi = lane >= 32;
  int4 r;
  r.x = hi ? b0 : a0;
  r.y = hi ? b1 : a1;
  r.z = hi ? b2 : a2;
  r.w = hi ? b3 : a3;
  return __builtin_bit_cast(s8v, r);
}

constexpr int KF_P = 72;          // kft/v1t pitch in shorts
constexpr int PART_SZ = 65 * 256; // trimmed partial tile

// ================= kv body (R6/R8, parametrized by item) =================
template <bool USE_PARTIAL>
__device__ inline void kv_body(int it, int tid,
                               const float* __restrict__ key,
                               const float* __restrict__ value,
                               const short* __restrict__ oh,
                               const short* __restrict__ ol,
                               short* __restrict__ partial,
                               float* __restrict__ kvacc,
                               short* kft, short* v1t) {
  const int lane = tid & 63, w = tid >> 6;
  const int b = it >> 6;
  const int s0 = (it & 63) * 128;
  const int q = lane >> 4, r15 = lane & 15;

  for (int i = tid; i < 15 * KF_P; i += 256) v1t[65 * KF_P + i] = 0;

  f4v acc[4][5];
#pragma unroll
  for (int j = 0; j < 4; ++j)
#pragma unroll
    for (int n = 0; n < 5; ++n) acc[j][n] = f4v{0.f, 0.f, 0.f, 0.f};

  for (int sc = 0; sc < 2; ++sc) {
    const int sbase = s0 + sc * 64;
    __syncthreads();
    {
      const float* vb = value + ((size_t)b * NT + sbase) * 64;
#pragma unroll
      for (int i = 0; i < 4; ++i) {
        int e4 = tid + i * 256;
        f4v v4 = ((const f4v*)vb)[e4];
        int s = e4 >> 4, d0 = (e4 & 15) * 4;
        v1t[(d0 + 0) * KF_P + s] = bf16_rne(v4.x);
        v1t[(d0 + 1) * KF_P + s] = bf16_rne(v4.y);
        v1t[(d0 + 2) * KF_P + s] = bf16_rne(v4.z);
        v1t[(d0 + 3) * KF_P + s] = bf16_rne(v4.w);
      }
      if (tid < 64) v1t[64 * KF_P + tid] = (short)0x3F80;  // bf16(1.0)
    }
    {
      PhiRows P;
      load_phi_rows(key + ((size_t)b * NT + sbase + w * 16) * 64, lane, P);
#pragma unroll
      for (int ft = 0; ft < 8; ++ft) {
        f4v c = phi_xw_tile(P, oh, ol, ft * 16, lane);
        s4v pk, nk;
#pragma unroll
        for (int reg = 0; reg < 4; ++reg) {
          float xw = c[reg];
          pk[reg] = bf16_rne((__expf(xw - P.ssr[reg]) + EPSF) * SCALE);
          nk[reg] = bf16_rne((__expf(-xw - P.ssr[reg]) + EPSF) * SCALE);
        }
        const int scol = w * 16 + q * 4;
        *(s4v*)(kft + (ft * 16 + r15) * KF_P + scol) = pk;
        *(s4v*)(kft + (128 + ft * 16 + r15) * KF_P + scol) = nk;
      }
    }
    __syncthreads();
#pragma unroll
    for (int ks = 0; ks < 2; ++ks) {
      s8v bf[5];
#pragma unroll
      for (int n = 0; n < 5; ++n)
        bf[n] = *(const s8v*)(v1t + (n * 16 + r15) * KF_P + ks * 32 + q * 8);
#pragma unroll
      for (int j = 0; j < 4; ++j) {
        s8v a = *(const s8v*)(kft + (w * 64 + j * 16 + r15) * KF_P + ks * 32 + q * 8);
#pragma unroll
        for (int n = 0; n < 5; ++n) acc[j][n] = mfma16(a, bf[n], acc[j][n]);
      }
    }
  }
  if (USE_PARTIAL) {
    short* pb = partial + (size_t)it * PART_SZ;
#pragma unroll
    for (int j = 0; j < 4; ++j) {
      int m = w * 64 + j * 16 + q * 4;
#pragma unroll
      for (int n = 0; n < 4; ++n) {
        int d = n * 16 + r15;
        s4v pk;
#pragma unroll
        for (int reg = 0; reg < 4; ++reg) pk[reg] = bf16_rne(acc[j][n][reg]);
        *(s4v*)(pb + d * 256 + m) = pk;
      }
      if (r15 == 0) {
        s4v pk;
#pragma unroll
        for (int reg = 0; reg < 4; ++reg) pk[reg] = bf16_rne(acc[j][4][reg]);
        *(s4v*)(pb + 64 * 256 + m) = pk;
      }
    }
  } else {
    float* pb = kvacc + (size_t)b * PART_SZ;
#pragma unroll
    for (int j = 0; j < 4; ++j) {
      int m = w * 64 + j * 16 + q * 4;
#pragma unroll
      for (int n = 0; n < 4; ++n) {
        int d = n * 16 + r15;
#pragma unroll
        for (int reg = 0; reg < 4; ++reg) atomicAdd(pb + d * 256 + m + reg, acc[j][n][reg]);
      }
      if (r15 == 0)
#pragma unroll
        for (int reg = 0; reg < 4; ++reg) atomicAdd(pb + 64 * 256 + m + reg, acc[j][4][reg]);
    }
  }
}

// ================= finalize body =================
__device__ inline void finalize_item(int i, const short* __restrict__ partial,
                                     short* __restrict__ kvfrag) {
  int b = i / 20480;
  int rem = i - b * 20480;
  int d = rem >> 8;
  int m = rem & 255;
  float s = 0.f;
  if (d < 65) {
    const short* p = partial + (size_t)(b * 64) * PART_SZ + d * 256 + m;
#pragma unroll 8
    for (int c = 0; c < 64; ++c) s += bf16_to_f(p[(size_t)c * PART_SZ]);
  }
  int ks = m >> 5, qq = (m >> 3) & 3, j = m & 7;
  int n = d >> 4, r = d & 15;
  int lane = qq * 16 + r;
  kvfrag[(((size_t)b * 40 + ks * 5 + n) * 64 + lane) * 8 + j] = bf16_rne(s);
}

// ================= qkv body (R8, parametrized by item) =================
__device__ inline void qkv_body(int it, int tid,
                                const float* __restrict__ query,
                                const short* __restrict__ oh,
                                const short* __restrict__ ol,
                                const short* __restrict__ kvfrag,
                                float* __restrict__ out, float* stg4) {
  const int lane = tid & 63, w = tid >> 6;
  const int b = it >> 7;
  const int t0 = (it & 127) * 64;
  const int q = lane >> 4, r15 = lane & 15;

  PhiRows P;
  load_phi_rows(query + ((size_t)b * NT + t0 + w * 16) * 64, lane, P);

  f4v acc[5];
#pragma unroll
  for (int n = 0; n < 5; ++n) acc[n] = f4v{0.f, 0.f, 0.f, 0.f};
  const short* kvb = kvfrag + (size_t)b * 40 * 512;

#pragma unroll
  for (int kp = 0; kp < 4; ++kp) {
    f4v c0 = phi_xw_tile_T(P, oh, ol, kp * 32, lane);
    f4v c1 = phi_xw_tile_T(P, oh, ol, kp * 32 + 16, lane);
    short p0[4], n0[4], p1[4], n1[4];
#pragma unroll
    for (int reg = 0; reg < 4; ++reg) {
      float x0 = c0[reg], x1 = c1[reg];
      p0[reg] = bf16_rne((__expf(x0 - P.ss) + EPSF) * SCALE);
      n0[reg] = bf16_rne((__expf(-x0 - P.ss) + EPSF) * SCALE);
      p1[reg] = bf16_rne((__expf(x1 - P.ss) + EPSF) * SCALE);
      n1[reg] = bf16_rne((__expf(-x1 - P.ss) + EPSF) * SCALE);
    }
    {
      s8v aP = bfrag_shuffle(pack2(p0[0], p0[1]), pack2(p0[2], p0[3]),
                             pack2(p1[0], p1[1]), pack2(p1[2], p1[3]), lane);
#pragma unroll
      for (int n = 0; n < 5; ++n) {
        s8v bf = *(const s8v*)(kvb + ((size_t)(kp * 5 + n)) * 512 + lane * 8);
        acc[n] = mfma16(aP, bf, acc[n]);
      }
    }
    {
      s8v aN = bfrag_shuffle(pack2(n0[0], n0[1]), pack2(n0[2], n0[3]),
                             pack2(n1[0], n1[1]), pack2(n1[2], n1[3]), lane);
#pragma unroll
      for (int n = 0; n < 5; ++n) {
        s8v bf = *(const s8v*)(kvb + ((size_t)((kp + 4) * 5 + n)) * 512 + lane * 8);
        acc[n] = mfma16(aN, bf, acc[n]);
      }
    }
  }
  float den_r[4];
#pragma unroll
  for (int reg = 0; reg < 4; ++reg) den_r[reg] = __shfl(acc[4][reg], lane & 48, 64);
  float* sg = stg4 + w * (16 * 68);
#pragma unroll
  for (int n = 0; n < 4; ++n)
#pragma unroll
    for (int reg = 0; reg < 4; ++reg) {
      int row = q * 4 + reg;
      int col = n * 16 + r15;
      sg[row * 68 + col] = acc[n][reg] / den_r[reg];
    }
  float* ob = out + ((size_t)b * NT + t0 + w * 16) * 64;
#pragma unroll
  for (int rr = 0; rr < 4; ++rr) {
    int row = rr * 4 + q;
    int c4 = r15 * 4;
    *(f4v*)(ob + row * 64 + c4) = *(const f4v*)(sg + row * 68 + c4);
  }
}

// ================= cooperative kernels =================
__global__ __launch_bounds__(256, 2) void coop_k1(
    const float* __restrict__ omega, const float* __restrict__ key,
    const float* __restrict__ value, short* __restrict__ oh,
    short* __restrict__ ol, short* __restrict__ partial) {
  __shared__ short kft[256 * KF_P];
  __shared__ short v1t[80 * KF_P];
  const int tid = threadIdx.x;
  // phase 0: omega split
  for (int i = blockIdx.x * 256 + tid; i < 128 * 64; i += gridDim.x * 256)
    omega_split_item(omega, oh, ol, i);
  __threadfence();
  cg::this_grid().sync();
  // phase 1: kv
  for (int it = blockIdx.x; it < 512; it += gridDim.x)
    kv_body<true>(it, tid, key, value, oh, ol, partial, nullptr, kft, v1t);
}

__global__ __launch_bounds__(256, 4) void coop_k2(
    const float* __restrict__ query, const short* __restrict__ oh,
    const short* __restrict__ ol, const short* __restrict__ partial,
    short* __restrict__ kvfrag, float* __restrict__ out) {
  __shared__ __align__(16) float stg[4 * 16 * 68];
  const int tid = threadIdx.x;
  // phase 0: finalize partials -> kvfrag
  for (int i = blockIdx.x * 256 + tid; i < 163840; i += gridDim.x * 256)
    finalize_item(i, partial, kvfrag);
  __threadfence();
  cg::this_grid().sync();
  // phase 1: qkv
  for (int it = blockIdx.x; it < 1024; it += gridDim.x)
    qkv_body(it, tid, query, oh, ol, kvfrag, out, stg);
}

// ================= standalone fallbacks (R8 path) =================
__global__ __launch_bounds__(256, 2) void kv_fused(
    const float* __restrict__ key, const float* __restrict__ value,
    const short* __restrict__ oh, const short* __restrict__ ol,
    short* __restrict__ partial, float* __restrict__ kvacc, int use_partial) {
  __shared__ short kft[256 * KF_P];
  __shared__ short v1t[80 * KF_P];
  if (use_partial)
    kv_body<true>(blockIdx.x, threadIdx.x, key, value, oh, ol, partial, kvacc, kft, v1t);
  else
    kv_body<false>(blockIdx.x, threadIdx.x, key, value, oh, ol, partial, kvacc, kft, v1t);
}

__global__ __launch_bounds__(256) void kv_finalize(
    const short* __restrict__ partial, const float* __restrict__ kvacc,
    short* __restrict__ kvfrag, int use_partial) {
  int i = blockIdx.x * 256 + threadIdx.x;
  if (use_partial) {
    finalize_item(i, partial, kvfrag);
  } else {
    int b = i / 20480;
    int rem = i - b * 20480;
    int d = rem >> 8;
    int m = rem & 255;
    float s = (d < 65) ? kvacc[(size_t)b * PART_SZ + d * 256 + m] : 0.f;
    int ks = m >> 5, qq = (m >> 3) & 3, j = m & 7;
    int n = d >> 4, r = d & 15;
    int lane = qq * 16 + r;
    kvfrag[(((size_t)b * 40 + ks * 5 + n) * 64 + lane) * 8 + j] = bf16_rne(s);
  }
}

__global__ __launch_bounds__(256, 4) void qkv_fused(
    const float* __restrict__ query, const short* __restrict__ oh,
    const short* __restrict__ ol, const short* __restrict__ kvfrag,
    float* __restrict__ out) {
  __shared__ __align__(16) float stg[4 * 16 * 68];
  qkv_body(blockIdx.x, threadIdx.x, query, oh, ol, kvfrag, out, stg);
}

extern "C" void kernel_launch(void* const* d_in, const int* in_sizes, int n_in,
                              void* d_out, int out_size, void* d_ws, size_t ws_size,
                              hipStream_t stream) {
  const float* query = (const float*)d_in[0];  // [8][8192][64]
  const float* value = (const float*)d_in[1];  // [8][8192][64]
  const float* key   = (const float*)d_in[2];  // [8][8192][64]
  const float* omega = (const float*)d_in[3];  // [128][64]
  float* out = (float*)d_out;

  char* ws = (char*)d_ws;
  short* oh = (short*)ws;                        // 16384 B
  short* ol = (short*)(ws + 16384);              // 16384 B
  short* kvfrag = (short*)(ws + 32768);          // 8*40*512*2 = 327680 B
  short* partial = (short*)(ws + 360448);        // 512*65*256*2 = 17039360 B
  float* kvacc = (float*)(ws + 360448);          // fallback: 8*65*256*4 = 532480 B
  const size_t need_full = 360448 + (size_t)512 * PART_SZ * 2;  // ~17.4 MB
  const int use_partial = (ws_size >= need_full) ? 1 : 0;

  bool did_k1 = false, did_k2 = false;
  if (use_partial) {
    int dev = 0;
    hipGetDevice(&dev);
    int num_cu = 0;
    hipDeviceGetAttribute(&num_cu, hipDeviceAttributeMultiprocessorCount, dev);
    int mb1 = 0, mb2 = 0;
    hipOccupancyMaxActiveBlocksPerMultiprocessor(&mb1, (const void*)coop_k1, 256, 0);
    hipOccupancyMaxActiveBlocksPerMultiprocessor(&mb2, (const void*)coop_k2, 256, 0);
    if ((long)mb1 * num_cu >= 512) {
      void* a1[] = {(void*)&omega, (void*)&key, (void*)&value,
                    (void*)&oh, (void*)&ol, (void*)&partial};
      did_k1 = (hipLaunchCooperativeKernel((void*)coop_k1, dim3(512), dim3(256),
                                           a1, 0, stream) == hipSuccess);
    }
    if (did_k1 && (long)mb2 * num_cu >= 1024) {
      void* a2[] = {(void*)&query, (void*)&oh, (void*)&ol,
                    (void*)&partial, (void*)&kvfrag, (void*)&out};
      did_k2 = (hipLaunchCooperativeKernel((void*)coop_k2, dim3(1024), dim3(256),
                                           a2, 0, stream) == hipSuccess);
    }
  }
  if (!did_k1) {
    setup_omega<<<32, 256, 0, stream>>>(omega, oh, ol);
    if (!use_partial) hipMemsetAsync(kvacc, 0, (size_t)8 * PART_SZ * 4, stream);
    kv_fused<<<512, 256, 0, stream>>>(key, value, oh, ol, partial, kvacc, use_partial);
  }
  if (!did_k2) {
    kv_finalize<<<640, 256, 0, stream>>>(partial, kvacc, kvfrag, use_partial);
    qkv_fused<<<1024, 256, 0, stream>>>(query, oh, ol, kvfrag, out);
  }
}